// Round 11
// baseline (184.454 us; speedup 1.0000x reference)
//
#include <hip/hip_runtime.h>

#define IN_DIM 128
#define HID_DIM 128
#define OUT_DIM 64

typedef short bf16x8 __attribute__((ext_vector_type(8)));   // 8 bf16 (4 VGPRs)
typedef float f32x4  __attribute__((ext_vector_type(4)));   // 4 fp32 acc

// ---- bf16 helpers (storage-only; math in fp32) ----
__device__ inline float bflo(unsigned int u) { return __uint_as_float(u << 16); }
__device__ inline float bfhi(unsigned int u) { return __uint_as_float(u & 0xffff0000u); }
__device__ inline unsigned short f2bf(float f) {
    unsigned int b = __float_as_uint(f);
    return (unsigned short)((b + 0x7FFFu + ((b >> 16) & 1u)) >> 16);  // RNE
}
__device__ inline unsigned int pack2(float a, float b) {
    return (unsigned int)f2bf(a) | ((unsigned int)f2bf(b) << 16);
}
__device__ inline float dot8(uint4 a, uint4 b) {
    return bflo(a.x) * bflo(b.x) + bfhi(a.x) * bfhi(b.x)
         + bflo(a.y) * bflo(b.y) + bfhi(a.y) * bfhi(b.y)
         + bflo(a.z) * bflo(b.z) + bfhi(a.z) * bfhi(b.z)
         + bflo(a.w) * bflo(b.w) + bfhi(a.w) * bfhi(b.w);
}

// ===========================================================================
// Zero cnt (custom; rocclr fill kernel bypass).
// ===========================================================================
__global__ void zero_cnt_kernel(uint4* __restrict__ p, int n4) {
    int i = blockIdx.x * blockDim.x + threadIdx.x;
    if (i < n4) p[i] = (uint4){0, 0, 0, 0};
}

// ===========================================================================
// Fused: blocks [0,24) transpose+convert weights (Wt1 [256][128], Wt2 [128][128]
// bf16); blocks [24, ...) do histogram + per-edge rank (atomic return).
// ===========================================================================
__global__ void wtrans_hist_kernel(const float* __restrict__ Ws1, const float* __restrict__ Wn1,
                                   const float* __restrict__ Ws2, const float* __restrict__ Wn2,
                                   unsigned short* __restrict__ Wt1, unsigned short* __restrict__ Wt2,
                                   const int* __restrict__ dst, int* __restrict__ cnt,
                                   unsigned short* __restrict__ rank, int E) {
    if ((int)blockIdx.x < 24) {
        int tid = (int)blockIdx.x * 256 + threadIdx.x;
        if (tid < 4096) {               // Wt1: 256 cols x 16 chunks of 8
            int c = tid >> 4, k0 = (tid & 15) << 3;
            const float* W = (c < 128) ? (Ws1 + c) : (Wn1 + (c - 128));
            ushort4 a, b;
            a.x = f2bf(W[(size_t)(k0 + 0) * 128]); a.y = f2bf(W[(size_t)(k0 + 1) * 128]);
            a.z = f2bf(W[(size_t)(k0 + 2) * 128]); a.w = f2bf(W[(size_t)(k0 + 3) * 128]);
            b.x = f2bf(W[(size_t)(k0 + 4) * 128]); b.y = f2bf(W[(size_t)(k0 + 5) * 128]);
            b.z = f2bf(W[(size_t)(k0 + 6) * 128]); b.w = f2bf(W[(size_t)(k0 + 7) * 128]);
            *(ushort4*)&Wt1[c * 128 + k0]     = a;
            *(ushort4*)&Wt1[c * 128 + k0 + 4] = b;
        } else if (tid < 6144) {        // Wt2: 128 cols x 16 chunks of 8
            int t = tid - 4096;
            int c = t >> 4, k0 = (t & 15) << 3;
            const float* W = (c < 64) ? (Ws2 + c) : (Wn2 + (c - 64));
            ushort4 a, b;
            a.x = f2bf(W[(size_t)(k0 + 0) * 64]); a.y = f2bf(W[(size_t)(k0 + 1) * 64]);
            a.z = f2bf(W[(size_t)(k0 + 2) * 64]); a.w = f2bf(W[(size_t)(k0 + 3) * 64]);
            b.x = f2bf(W[(size_t)(k0 + 4) * 64]); b.y = f2bf(W[(size_t)(k0 + 5) * 64]);
            b.z = f2bf(W[(size_t)(k0 + 6) * 64]); b.w = f2bf(W[(size_t)(k0 + 7) * 64]);
            *(ushort4*)&Wt2[c * 128 + k0]     = a;
            *(ushort4*)&Wt2[c * 128 + k0 + 4] = b;
        }
        return;
    }
    int e = ((int)blockIdx.x - 24) * 256 + threadIdx.x;
    if (e < E) rank[e] = (unsigned short)atomicAdd(&cnt[dst[e]], 1);
}

// ===========================================================================
// Scan step 1: per-256-chunk sums.
// ===========================================================================
__global__ void block_sums_kernel(const int* __restrict__ cnt, int* __restrict__ partial, int N) {
    __shared__ int s[256];
    int i = blockIdx.x * 256 + threadIdx.x;
    s[threadIdx.x] = (i < N) ? cnt[i] : 0;
    __syncthreads();
    for (int o = 128; o > 0; o >>= 1) {
        if (threadIdx.x < o) s[threadIdx.x] += s[threadIdx.x + o];
        __syncthreads();
    }
    if (threadIdx.x == 0) partial[blockIdx.x] = s[0];
}

// ===========================================================================
// Scan step 2: each block reduces partial[0..blockIdx) itself (NB<=256),
// then in-block exclusive scan of its cnt chunk -> row_ptr.
// ===========================================================================
__global__ void scan_chunks_kernel(const int* __restrict__ cnt, const int* __restrict__ partial,
                                   int* __restrict__ row_ptr, int N, int NB) {
    __shared__ int s[256];
    const int t = threadIdx.x;
    s[t] = (t < NB && t < (int)blockIdx.x) ? partial[t] : 0;
    __syncthreads();
    for (int o = 128; o > 0; o >>= 1) {
        if (t < o) s[t] += s[t + o];
        __syncthreads();
    }
    const int base = s[0];
    __syncthreads();
    int i = blockIdx.x * 256 + t;
    int v = (i < N) ? cnt[i] : 0;
    s[t] = v;
    __syncthreads();
    for (int o = 1; o < 256; o <<= 1) {
        int tv = (t >= o) ? s[t - o] : 0;
        __syncthreads();
        s[t] += tv;
        __syncthreads();
    }
    int incl = s[t];
    if (i < N) row_ptr[i] = base + incl - v;
    if (i == N - 1) row_ptr[N] = base + incl;
}

// ===========================================================================
// Fused layer-1: blocks [0, FB) = non-atomic CSR scatter; blocks [FB, FB+NT)
// = one 32-node MFMA dual-GEMM tile (MT=32: 2x the blocks of MT=64 -> better
// latency hiding; weights stay L2-resident so the extra re-reads are cheap).
// GEMM: hsb[n] = bf16(x[n]@Ws1 + b1) ; t[n] = bf16(x[n]@Wn1).
// ===========================================================================
__global__ __launch_bounds__(256) void gemm1_fill_kernel(
        const float* __restrict__ x,
        const unsigned short* __restrict__ Wt,   // [256][128] bf16
        const float* __restrict__ bias,
        unsigned short* __restrict__ hsb,
        unsigned short* __restrict__ t,
        int N, int FB,
        const int* __restrict__ src,
        const int* __restrict__ dst,
        const int* __restrict__ row_ptr,
        const unsigned short* __restrict__ rank,
        unsigned short* __restrict__ col_src,
        int E) {
    constexpr int DOUT = HID_DIM;
    constexpr int K   = 128;
    constexpr int MT  = 32;             // node tile (was 64)
    constexpr int SL  = 2 * DOUT / 4;   // 64 cols per wave
    constexpr int TN  = SL / 16;        // 4
    constexpr int TM  = MT / 16;        // 2
    constexpr int KS  = K / 32;         // 4
    constexpr int LDA = K + 8;

    __shared__ unsigned short sA[MT][LDA];

    const int tid = threadIdx.x;

    if ((int)blockIdx.x < FB) {
        int base = (int)blockIdx.x * 1024;
        #pragma unroll
        for (int k = 0; k < 4; ++k) {
            int e = base + k * 256 + tid;
            if (e < E) {
                int d = dst[e];
                col_src[row_ptr[d] + (int)rank[e]] = (unsigned short)src[e];
            }
        }
        return;
    }

    const int w   = tid >> 6;
    const int l   = tid & 63;
    const int l16 = l & 15;
    const int lhi = l >> 4;
    const int n0  = ((int)blockIdx.x - FB) * MT;

    // ---- stage A tile: 32 x 128 fp32 -> bf16 in LDS ----
    #pragma unroll
    for (int it = 0; it < 4; ++it) {
        int flat = it * 256 + tid;       // 0..1023 (32 rows x 32 float4)
        int r  = flat >> 5;
        int c4 = flat & 31;
        float4 v = {0, 0, 0, 0};
        if (n0 + r < N) v = *(const float4*)&x[(size_t)(n0 + r) * K + c4 * 4];
        ushort4 p;
        p.x = f2bf(v.x); p.y = f2bf(v.y); p.z = f2bf(v.z); p.w = f2bf(v.w);
        *(ushort4*)&sA[r][c4 * 4] = p;
    }

    // ---- weight fragments: one 16B load each ----
    bf16x8 breg[TN][KS];
    float  bval[TN];
    #pragma unroll
    for (int tn = 0; tn < TN; ++tn) {
        const int c = w * SL + tn * 16 + l16;
        bval[tn] = (c < DOUT) ? bias[c] : 0.0f;
        #pragma unroll
        for (int ks = 0; ks < KS; ++ks)
            breg[tn][ks] = *(const bf16x8*)&Wt[c * 128 + ks * 32 + lhi * 8];
    }
    __syncthreads();

    f32x4 acc[TN][TM];
    #pragma unroll
    for (int tn = 0; tn < TN; ++tn)
        #pragma unroll
        for (int tm = 0; tm < TM; ++tm)
            acc[tn][tm] = (f32x4){0.0f, 0.0f, 0.0f, 0.0f};

    #pragma unroll
    for (int ks = 0; ks < KS; ++ks) {
        bf16x8 a[TM];
        #pragma unroll
        for (int tm = 0; tm < TM; ++tm)
            a[tm] = *(const bf16x8*)&sA[tm * 16 + l16][ks * 32 + lhi * 8];
        #pragma unroll
        for (int tn = 0; tn < TN; ++tn)
            #pragma unroll
            for (int tm = 0; tm < TM; ++tm)
                acc[tn][tm] = __builtin_amdgcn_mfma_f32_16x16x32_bf16(
                    a[tm], breg[tn][ks], acc[tn][tm], 0, 0, 0);
    }

    // ---- epilogue: C/D layout col=lane&15, row=(lane>>4)*4+r ----
    #pragma unroll
    for (int tn = 0; tn < TN; ++tn) {
        const int c = w * SL + tn * 16 + l16;
        const bool self = (c < DOUT);
        const int cc = self ? c : c - DOUT;
        #pragma unroll
        for (int tm = 0; tm < TM; ++tm) {
            #pragma unroll
            for (int r = 0; r < 4; ++r) {
                const int n = n0 + tm * 16 + lhi * 4 + r;
                if (n < N) {
                    const unsigned short v = f2bf(acc[tn][tm][r] + bval[tn]);
                    if (self) hsb[(size_t)n * DOUT + cc] = v;
                    else      t  [(size_t)n * DOUT + cc] = v;
                }
            }
        }
    }
}

// ===========================================================================
// Gather-mean layer 1 (D=128): one 64-lane wave per node.
// out (bf16) = relu(base(bf16) + mean t[neighbors])
// ===========================================================================
__global__ void gather_mean128_kernel(const unsigned short* __restrict__ t,
                                      const unsigned short* __restrict__ base,
                                      const int* __restrict__ row_ptr,
                                      const unsigned short* __restrict__ col_src,
                                      unsigned short* __restrict__ out, int N) {
    int node = (blockIdx.x * blockDim.x + threadIdx.x) >> 6;
    int lane = threadIdx.x & 63;
    if (node >= N) return;
    const int beg = row_ptr[node], end = row_ptr[node + 1];
    const float rdeg = 1.0f / fmaxf((float)(end - beg), 1.0f);
    const int off = lane * 2;

    float a0x = 0, a0y = 0, a1x = 0, a1y = 0, a2x = 0, a2y = 0, a3x = 0, a3y = 0;
    int i = beg;
    for (; i + 4 <= end; i += 4) {
        int s0 = col_src[i], s1 = col_src[i + 1], s2 = col_src[i + 2], s3 = col_src[i + 3];
        unsigned int u0 = *(const unsigned int*)&t[(size_t)s0 * 128 + off];
        unsigned int u1 = *(const unsigned int*)&t[(size_t)s1 * 128 + off];
        unsigned int u2 = *(const unsigned int*)&t[(size_t)s2 * 128 + off];
        unsigned int u3 = *(const unsigned int*)&t[(size_t)s3 * 128 + off];
        a0x += bflo(u0); a0y += bfhi(u0);
        a1x += bflo(u1); a1y += bfhi(u1);
        a2x += bflo(u2); a2y += bfhi(u2);
        a3x += bflo(u3); a3y += bfhi(u3);
    }
    for (; i < end; ++i) {
        unsigned int u = *(const unsigned int*)&t[(size_t)col_src[i] * 128 + off];
        a0x += bflo(u); a0y += bfhi(u);
    }
    float ax = (a0x + a1x) + (a2x + a3x);
    float ay = (a0y + a1y) + (a2y + a3y);
    unsigned int ub = *(const unsigned int*)&base[(size_t)node * 128 + off];
    float ox = fmaxf(bflo(ub) + ax * rdeg, 0.0f);
    float oy = fmaxf(bfhi(ub) + ay * rdeg, 0.0f);
    *(unsigned int*)&out[(size_t)node * 128 + off] = pack2(ox, oy);
}

// ===========================================================================
// Layer-2 MFMA dual GEMM, bf16 input (h1), weights from Wt2; bf16 outputs.
// ===========================================================================
__global__ __launch_bounds__(256) void gemm2_kernel(
        const unsigned short* __restrict__ x,   // h1 bf16 [N][128]
        const unsigned short* __restrict__ Wt,  // [128][128] bf16
        const float* __restrict__ bias,
        unsigned short* __restrict__ hsb2,
        unsigned short* __restrict__ t2,
        int N) {
    constexpr int DOUT = OUT_DIM;
    constexpr int K   = 128;
    constexpr int MT  = 64;
    constexpr int SL  = 2 * DOUT / 4;   // 32
    constexpr int TN  = SL / 16;        // 2
    constexpr int TM  = MT / 16;        // 4
    constexpr int KS  = K / 32;         // 4
    constexpr int LDA = K + 8;

    __shared__ unsigned short sA[MT][LDA];

    const int tid = threadIdx.x;
    const int w   = tid >> 6;
    const int l   = tid & 63;
    const int l16 = l & 15;
    const int lhi = l >> 4;
    const int n0  = (int)blockIdx.x * MT;

    // ---- stage A tile: 64 x 128 bf16 copy ----
    #pragma unroll
    for (int it = 0; it < 4; ++it) {
        int flat = it * 256 + tid;
        int r  = flat >> 4;
        int c8 = flat & 15;
        uint4 v = {0, 0, 0, 0};
        if (n0 + r < N) v = *(const uint4*)&x[(size_t)(n0 + r) * K + c8 * 8];
        *(uint4*)&sA[r][c8 * 8] = v;
    }

    bf16x8 breg[TN][KS];
    float  bval[TN];
    #pragma unroll
    for (int tn = 0; tn < TN; ++tn) {
        const int c = w * SL + tn * 16 + l16;
        bval[tn] = (c < DOUT) ? bias[c] : 0.0f;
        #pragma unroll
        for (int ks = 0; ks < KS; ++ks)
            breg[tn][ks] = *(const bf16x8*)&Wt[c * 128 + ks * 32 + lhi * 8];
    }
    __syncthreads();

    f32x4 acc[TN][TM];
    #pragma unroll
    for (int tn = 0; tn < TN; ++tn)
        #pragma unroll
        for (int tm = 0; tm < TM; ++tm)
            acc[tn][tm] = (f32x4){0.0f, 0.0f, 0.0f, 0.0f};

    #pragma unroll
    for (int ks = 0; ks < KS; ++ks) {
        bf16x8 a[TM];
        #pragma unroll
        for (int tm = 0; tm < TM; ++tm)
            a[tm] = *(const bf16x8*)&sA[tm * 16 + l16][ks * 32 + lhi * 8];
        #pragma unroll
        for (int tn = 0; tn < TN; ++tn)
            #pragma unroll
            for (int tm = 0; tm < TM; ++tm)
                acc[tn][tm] = __builtin_amdgcn_mfma_f32_16x16x32_bf16(
                    a[tm], breg[tn][ks], acc[tn][tm], 0, 0, 0);
    }

    #pragma unroll
    for (int tn = 0; tn < TN; ++tn) {
        const int c = w * SL + tn * 16 + l16;
        const bool self = (c < DOUT);
        const int cc = self ? c : c - DOUT;
        #pragma unroll
        for (int tm = 0; tm < TM; ++tm) {
            #pragma unroll
            for (int r = 0; r < 4; ++r) {
                const int n = n0 + tm * 16 + lhi * 4 + r;
                if (n < N) {
                    const unsigned short v = f2bf(acc[tn][tm][r] + bval[tn]);
                    if (self) hsb2[(size_t)n * DOUT + cc] = v;
                    else      t2  [(size_t)n * DOUT + cc] = v;
                }
            }
        }
    }
}

// ===========================================================================
// Gather-mean layer 2 (D=64): 32 lanes per node (2 nodes/wave), bf16 base/out.
// ===========================================================================
__global__ void gather_mean64_kernel(const unsigned short* __restrict__ t,
                                     const unsigned short* __restrict__ base,
                                     const int* __restrict__ row_ptr,
                                     const unsigned short* __restrict__ col_src,
                                     unsigned short* __restrict__ out, int N) {
    int tid  = blockIdx.x * blockDim.x + threadIdx.x;
    int node = (tid >> 6) * 2 + ((tid >> 5) & 1);
    int m    = tid & 31;
    if (node >= N) return;
    const int beg = row_ptr[node], end = row_ptr[node + 1];
    const float rdeg = 1.0f / fmaxf((float)(end - beg), 1.0f);
    const int off = m * 2;

    float a0x = 0, a0y = 0, a1x = 0, a1y = 0, a2x = 0, a2y = 0, a3x = 0, a3y = 0;
    int i = beg;
    for (; i + 4 <= end; i += 4) {
        int s0 = col_src[i], s1 = col_src[i + 1], s2 = col_src[i + 2], s3 = col_src[i + 3];
        unsigned int u0 = *(const unsigned int*)&t[(size_t)s0 * 64 + off];
        unsigned int u1 = *(const unsigned int*)&t[(size_t)s1 * 64 + off];
        unsigned int u2 = *(const unsigned int*)&t[(size_t)s2 * 64 + off];
        unsigned int u3 = *(const unsigned int*)&t[(size_t)s3 * 64 + off];
        a0x += bflo(u0); a0y += bfhi(u0);
        a1x += bflo(u1); a1y += bfhi(u1);
        a2x += bflo(u2); a2y += bfhi(u2);
        a3x += bflo(u3); a3y += bfhi(u3);
    }
    for (; i < end; ++i) {
        unsigned int u = *(const unsigned int*)&t[(size_t)col_src[i] * 64 + off];
        a0x += bflo(u); a0y += bfhi(u);
    }
    float ax = (a0x + a1x) + (a2x + a3x);
    float ay = (a0y + a1y) + (a2y + a3y);
    unsigned int ub = *(const unsigned int*)&base[(size_t)node * 64 + off];
    *(unsigned int*)&out[(size_t)node * 64 + off] =
        pack2(bflo(ub) + ax * rdeg, bfhi(ub) + ay * rdeg);
}

// ===========================================================================
// Edge dot on bf16 h (D=64, 128B rows): 4 lanes per edge-PAIR slot, 2 edges
// per 4-lane group -> 8 independent 16B gathers per lane (2x ILP), coalesced
// float2 output write per pair.
// ===========================================================================
__global__ void edge_dot_kernel(const unsigned short* __restrict__ h,
                                const int* __restrict__ src,
                                const int* __restrict__ dst,
                                const int* __restrict__ nsrc,
                                const int* __restrict__ ndst,
                                float* __restrict__ out,
                                int E) {
    int tid = blockIdx.x * blockDim.x + threadIdx.x;
    int g = tid >> 2;              // group handles edges 2g, 2g+1
    int l = tid & 3;
    int e0 = g * 2;
    if (e0 >= 2 * E) return;
    int e1 = e0 + 1;
    const bool has1 = (e1 < 2 * E);

    int s0, t0;
    if (e0 < E) { s0 = src[e0];      t0 = dst[e0]; }
    else        { s0 = nsrc[e0 - E]; t0 = ndst[e0 - E]; }
    int s1 = s0, t1 = t0;
    if (has1) {
        if (e1 < E) { s1 = src[e1];      t1 = dst[e1]; }
        else        { s1 = nsrc[e1 - E]; t1 = ndst[e1 - E]; }
    }

    const uint4* pa0 = (const uint4*)&h[(size_t)s0 * OUT_DIM + l * 16];
    const uint4* pb0 = (const uint4*)&h[(size_t)t0 * OUT_DIM + l * 16];
    const uint4* pa1 = (const uint4*)&h[(size_t)s1 * OUT_DIM + l * 16];
    const uint4* pb1 = (const uint4*)&h[(size_t)t1 * OUT_DIM + l * 16];
    uint4 a00 = pa0[0], a01 = pa0[1];
    uint4 b00 = pb0[0], b01 = pb0[1];
    uint4 a10 = pa1[0], a11 = pa1[1];
    uint4 b10 = pb1[0], b11 = pb1[1];

    float v0 = dot8(a00, b00) + dot8(a01, b01);
    float v1 = dot8(a10, b10) + dot8(a11, b11);
    v0 += __shfl_xor(v0, 2, 4);
    v0 += __shfl_xor(v0, 1, 4);
    v1 += __shfl_xor(v1, 2, 4);
    v1 += __shfl_xor(v1, 1, 4);
    if (l == 0) {
        if (has1) {
            float2 o = {v0, v1};
            *(float2*)&out[e0] = o;
        } else {
            out[e0] = v0;
        }
    }
}

extern "C" void kernel_launch(void* const* d_in, const int* in_sizes, int n_in,
                              void* d_out, int out_size, void* d_ws, size_t ws_size,
                              hipStream_t stream) {
    const float* feat = (const float*)d_in[0];
    const float* Ws1  = (const float*)d_in[1];
    const float* Wn1  = (const float*)d_in[2];
    const float* b1   = (const float*)d_in[3];
    const float* Ws2  = (const float*)d_in[4];
    const float* Wn2  = (const float*)d_in[5];
    const float* b2   = (const float*)d_in[6];
    const int* src  = (const int*)d_in[7];
    const int* dst  = (const int*)d_in[8];
    const int* nsrc = (const int*)d_in[9];
    const int* ndst = (const int*)d_in[10];
    const int E = in_sizes[7];
    const int N = in_sizes[0] / IN_DIM;
    const int NB = (N + 255) / 256;
    const int NT1 = (N + 31) / 32;          // layer-1 MFMA tiles (MT=32)
    const int NT2 = (N + 63) / 64;          // layer-2 MFMA tiles (MT=64)
    const int FB = (E + 1023) / 1024;       // scatter blocks
    const int HB = (E + 255) / 256;         // hist blocks

    // ---- workspace layout (16B-aligned big arrays first) ----
    char* wsb = (char*)d_ws;
    unsigned short* Wt1  = (unsigned short*)wsb;                         // [256][128]
    unsigned short* Wt2  = Wt1 + 256 * 128;                              // [128][128]
    unsigned short* t1   = Wt2 + 128 * 128;                              // N*128 bf16
    unsigned short* hs1b = t1 + (size_t)N * HID_DIM;                     // N*128 bf16
    unsigned short* h1   = hs1b + (size_t)N * HID_DIM;                   // N*128 bf16
    unsigned short* t2   = h1 + (size_t)N * HID_DIM;                     // N*64 bf16
    unsigned short* hs2b = t2 + (size_t)N * OUT_DIM;                     // N*64 bf16
    unsigned short* h2   = hs2b + (size_t)N * OUT_DIM;                   // N*64 bf16
    int* cnt             = (int*)(h2 + (size_t)N * OUT_DIM);             // N
    int* row_ptr         = cnt + N;                                      // N+1
    int* partial         = row_ptr + N + 1;                              // 256
    unsigned short* rank    = (unsigned short*)(partial + 256);          // E
    unsigned short* col_src = rank + E;                                  // E

    // ---- zero cnt ----
    {
        int n4 = (N + 3) / 4;
        zero_cnt_kernel<<<(n4 + 255) / 256, 256, 0, stream>>>((uint4*)cnt, n4);
    }

    // ---- CSR build + weight transpose (fused) ----
    wtrans_hist_kernel<<<24 + HB, 256, 0, stream>>>(
        Ws1, Wn1, Ws2, Wn2, Wt1, Wt2, dst, cnt, rank, E);
    block_sums_kernel<<<NB, 256, 0, stream>>>(cnt, partial, N);
    scan_chunks_kernel<<<NB, 256, 0, stream>>>(cnt, partial, row_ptr, N, NB);

    // ---- Layer 1 GEMM (MT=32, 1 tile/block) fused with non-atomic scatter ----
    gemm1_fill_kernel<<<FB + NT1, 256, 0, stream>>>(
        feat, Wt1, b1, hs1b, t1, N, FB,
        src, dst, row_ptr, rank, col_src, E);

    // ---- Layer 1 gather-mean + relu -> h1 (bf16; one wave per node) ----
    gather_mean128_kernel<<<(N * 64 + 255) / 256, 256, 0, stream>>>(
        t1, hs1b, row_ptr, col_src, h1, N);

    // ---- Layer 2 GEMM (bf16 input) ----
    gemm2_kernel<<<NT2, 256, 0, stream>>>(
        h1, Wt2, b2, hs2b, t2, N);

    // ---- Layer 2 gather-mean -> h2 (bf16) ----
    {
        int waves = (N + 1) / 2;
        gather_mean64_kernel<<<(waves * 64 + 255) / 256, 256, 0, stream>>>(
            t2, hs2b, row_ptr, col_src, h2, N);
    }

    // ---- Edge dots (2 edges per 4-lane group) ----
    {
        int groups = (2 * E + 1) / 2;
        int total = groups * 4;
        edge_dot_kernel<<<(total + 255) / 256, 256, 0, stream>>>(
            h2, src, dst, nsrc, ndst, (float*)d_out, E);
    }
}

// Round 12
// 182.278 us; speedup vs baseline: 1.0119x; 1.0119x over previous
//
#include <hip/hip_runtime.h>

#define IN_DIM 128
#define HID_DIM 128
#define OUT_DIM 64

typedef short bf16x8 __attribute__((ext_vector_type(8)));   // 8 bf16 (4 VGPRs)
typedef float f32x4  __attribute__((ext_vector_type(4)));   // 4 fp32 acc

// ---- bf16 helpers (storage-only; math in fp32) ----
__device__ inline float bflo(unsigned int u) { return __uint_as_float(u << 16); }
__device__ inline float bfhi(unsigned int u) { return __uint_as_float(u & 0xffff0000u); }
__device__ inline unsigned short f2bf(float f) {
    unsigned int b = __float_as_uint(f);
    return (unsigned short)((b + 0x7FFFu + ((b >> 16) & 1u)) >> 16);  // RNE
}
__device__ inline unsigned int pack2(float a, float b) {
    return (unsigned int)f2bf(a) | ((unsigned int)f2bf(b) << 16);
}
__device__ inline float dot8(uint4 a, uint4 b) {
    return bflo(a.x) * bflo(b.x) + bfhi(a.x) * bfhi(b.x)
         + bflo(a.y) * bflo(b.y) + bfhi(a.y) * bfhi(b.y)
         + bflo(a.z) * bflo(b.z) + bfhi(a.z) * bfhi(b.z)
         + bflo(a.w) * bflo(b.w) + bfhi(a.w) * bfhi(b.w);
}

// ===========================================================================
// Zero cnt (custom; rocclr fill kernel bypass).
// ===========================================================================
__global__ void zero_cnt_kernel(uint4* __restrict__ p, int n4) {
    int i = blockIdx.x * blockDim.x + threadIdx.x;
    if (i < n4) p[i] = (uint4){0, 0, 0, 0};
}

// ===========================================================================
// Fused: blocks [0,24) transpose+convert weights (Wt1 [256][128], Wt2 [128][128]
// bf16); blocks [24, ...) do histogram + per-edge rank (atomic return).
// ===========================================================================
__global__ void wtrans_hist_kernel(const float* __restrict__ Ws1, const float* __restrict__ Wn1,
                                   const float* __restrict__ Ws2, const float* __restrict__ Wn2,
                                   unsigned short* __restrict__ Wt1, unsigned short* __restrict__ Wt2,
                                   const int* __restrict__ dst, int* __restrict__ cnt,
                                   unsigned short* __restrict__ rank, int E) {
    if ((int)blockIdx.x < 24) {
        int tid = (int)blockIdx.x * 256 + threadIdx.x;
        if (tid < 4096) {               // Wt1: 256 cols x 16 chunks of 8
            int c = tid >> 4, k0 = (tid & 15) << 3;
            const float* W = (c < 128) ? (Ws1 + c) : (Wn1 + (c - 128));
            ushort4 a, b;
            a.x = f2bf(W[(size_t)(k0 + 0) * 128]); a.y = f2bf(W[(size_t)(k0 + 1) * 128]);
            a.z = f2bf(W[(size_t)(k0 + 2) * 128]); a.w = f2bf(W[(size_t)(k0 + 3) * 128]);
            b.x = f2bf(W[(size_t)(k0 + 4) * 128]); b.y = f2bf(W[(size_t)(k0 + 5) * 128]);
            b.z = f2bf(W[(size_t)(k0 + 6) * 128]); b.w = f2bf(W[(size_t)(k0 + 7) * 128]);
            *(ushort4*)&Wt1[c * 128 + k0]     = a;
            *(ushort4*)&Wt1[c * 128 + k0 + 4] = b;
        } else if (tid < 6144) {        // Wt2: 128 cols x 16 chunks of 8
            int t = tid - 4096;
            int c = t >> 4, k0 = (t & 15) << 3;
            const float* W = (c < 64) ? (Ws2 + c) : (Wn2 + (c - 64));
            ushort4 a, b;
            a.x = f2bf(W[(size_t)(k0 + 0) * 64]); a.y = f2bf(W[(size_t)(k0 + 1) * 64]);
            a.z = f2bf(W[(size_t)(k0 + 2) * 64]); a.w = f2bf(W[(size_t)(k0 + 3) * 64]);
            b.x = f2bf(W[(size_t)(k0 + 4) * 64]); b.y = f2bf(W[(size_t)(k0 + 5) * 64]);
            b.z = f2bf(W[(size_t)(k0 + 6) * 64]); b.w = f2bf(W[(size_t)(k0 + 7) * 64]);
            *(ushort4*)&Wt2[c * 128 + k0]     = a;
            *(ushort4*)&Wt2[c * 128 + k0 + 4] = b;
        }
        return;
    }
    int e = ((int)blockIdx.x - 24) * 256 + threadIdx.x;
    if (e < E) rank[e] = (unsigned short)atomicAdd(&cnt[dst[e]], 1);
}

// ===========================================================================
// Scan step 1: per-256-chunk sums.
// ===========================================================================
__global__ void block_sums_kernel(const int* __restrict__ cnt, int* __restrict__ partial, int N) {
    __shared__ int s[256];
    int i = blockIdx.x * 256 + threadIdx.x;
    s[threadIdx.x] = (i < N) ? cnt[i] : 0;
    __syncthreads();
    for (int o = 128; o > 0; o >>= 1) {
        if (threadIdx.x < o) s[threadIdx.x] += s[threadIdx.x + o];
        __syncthreads();
    }
    if (threadIdx.x == 0) partial[blockIdx.x] = s[0];
}

// ===========================================================================
// Scan step 2: each block reduces partial[0..blockIdx) itself (NB<=256),
// then in-block exclusive scan of its cnt chunk -> row_ptr.
// ===========================================================================
__global__ void scan_chunks_kernel(const int* __restrict__ cnt, const int* __restrict__ partial,
                                   int* __restrict__ row_ptr, int N, int NB) {
    __shared__ int s[256];
    const int t = threadIdx.x;
    s[t] = (t < NB && t < (int)blockIdx.x) ? partial[t] : 0;
    __syncthreads();
    for (int o = 128; o > 0; o >>= 1) {
        if (t < o) s[t] += s[t + o];
        __syncthreads();
    }
    const int base = s[0];
    __syncthreads();
    int i = blockIdx.x * 256 + t;
    int v = (i < N) ? cnt[i] : 0;
    s[t] = v;
    __syncthreads();
    for (int o = 1; o < 256; o <<= 1) {
        int tv = (t >= o) ? s[t - o] : 0;
        __syncthreads();
        s[t] += tv;
        __syncthreads();
    }
    int incl = s[t];
    if (i < N) row_ptr[i] = base + incl - v;
    if (i == N - 1) row_ptr[N] = base + incl;
}

// ===========================================================================
// Fused layer-1: blocks [0, FB) = non-atomic CSR scatter; blocks [FB, FB+NT)
// = one 64-node MFMA dual-GEMM tile (weights from pre-transposed Wt1).
// GEMM: hsb[n] = bf16(x[n]@Ws1 + b1) ; t[n] = bf16(x[n]@Wn1).
// ===========================================================================
__global__ __launch_bounds__(256) void gemm1_fill_kernel(
        const float* __restrict__ x,
        const unsigned short* __restrict__ Wt,   // [256][128] bf16
        const float* __restrict__ bias,
        unsigned short* __restrict__ hsb,
        unsigned short* __restrict__ t,
        int N, int FB,
        const int* __restrict__ src,
        const int* __restrict__ dst,
        const int* __restrict__ row_ptr,
        const unsigned short* __restrict__ rank,
        unsigned short* __restrict__ col_src,
        int E) {
    constexpr int DOUT = HID_DIM;
    constexpr int K   = 128;
    constexpr int MT  = 64;
    constexpr int SL  = 2 * DOUT / 4;   // 64 cols per wave
    constexpr int TN  = SL / 16;        // 4
    constexpr int TM  = MT / 16;        // 4
    constexpr int KS  = K / 32;         // 4
    constexpr int LDA = K + 8;

    __shared__ unsigned short sA[MT][LDA];

    const int tid = threadIdx.x;

    if ((int)blockIdx.x < FB) {
        int base = (int)blockIdx.x * 1024;
        #pragma unroll
        for (int k = 0; k < 4; ++k) {
            int e = base + k * 256 + tid;
            if (e < E) {
                int d = dst[e];
                col_src[row_ptr[d] + (int)rank[e]] = (unsigned short)src[e];
            }
        }
        return;
    }

    const int w   = tid >> 6;
    const int l   = tid & 63;
    const int l16 = l & 15;
    const int lhi = l >> 4;
    const int n0  = ((int)blockIdx.x - FB) * MT;

    // ---- stage A tile: 64 x 128 fp32 -> bf16 in LDS ----
    #pragma unroll
    for (int it = 0; it < 8; ++it) {
        int flat = it * 256 + tid;
        int r  = flat >> 5;
        int c4 = flat & 31;
        float4 v = {0, 0, 0, 0};
        if (n0 + r < N) v = *(const float4*)&x[(size_t)(n0 + r) * K + c4 * 4];
        ushort4 p;
        p.x = f2bf(v.x); p.y = f2bf(v.y); p.z = f2bf(v.z); p.w = f2bf(v.w);
        *(ushort4*)&sA[r][c4 * 4] = p;
    }

    // ---- weight fragments: one 16B load each ----
    bf16x8 breg[TN][KS];
    float  bval[TN];
    #pragma unroll
    for (int tn = 0; tn < TN; ++tn) {
        const int c = w * SL + tn * 16 + l16;
        bval[tn] = (c < DOUT) ? bias[c] : 0.0f;
        #pragma unroll
        for (int ks = 0; ks < KS; ++ks)
            breg[tn][ks] = *(const bf16x8*)&Wt[c * 128 + ks * 32 + lhi * 8];
    }
    __syncthreads();

    f32x4 acc[TN][TM];
    #pragma unroll
    for (int tn = 0; tn < TN; ++tn)
        #pragma unroll
        for (int tm = 0; tm < TM; ++tm)
            acc[tn][tm] = (f32x4){0.0f, 0.0f, 0.0f, 0.0f};

    #pragma unroll
    for (int ks = 0; ks < KS; ++ks) {
        bf16x8 a[TM];
        #pragma unroll
        for (int tm = 0; tm < TM; ++tm)
            a[tm] = *(const bf16x8*)&sA[tm * 16 + l16][ks * 32 + lhi * 8];
        #pragma unroll
        for (int tn = 0; tn < TN; ++tn)
            #pragma unroll
            for (int tm = 0; tm < TM; ++tm)
                acc[tn][tm] = __builtin_amdgcn_mfma_f32_16x16x32_bf16(
                    a[tm], breg[tn][ks], acc[tn][tm], 0, 0, 0);
    }

    // ---- epilogue: C/D layout col=lane&15, row=(lane>>4)*4+r ----
    #pragma unroll
    for (int tn = 0; tn < TN; ++tn) {
        const int c = w * SL + tn * 16 + l16;
        const bool self = (c < DOUT);
        const int cc = self ? c : c - DOUT;
        #pragma unroll
        for (int tm = 0; tm < TM; ++tm) {
            #pragma unroll
            for (int r = 0; r < 4; ++r) {
                const int n = n0 + tm * 16 + lhi * 4 + r;
                if (n < N) {
                    const unsigned short v = f2bf(acc[tn][tm][r] + bval[tn]);
                    if (self) hsb[(size_t)n * DOUT + cc] = v;
                    else      t  [(size_t)n * DOUT + cc] = v;
                }
            }
        }
    }
}

// ===========================================================================
// Gather-mean layer 1 (D=128): one 64-lane wave per node.
// out (bf16) = relu(base(bf16) + mean t[neighbors])
// ===========================================================================
__global__ void gather_mean128_kernel(const unsigned short* __restrict__ t,
                                      const unsigned short* __restrict__ base,
                                      const int* __restrict__ row_ptr,
                                      const unsigned short* __restrict__ col_src,
                                      unsigned short* __restrict__ out, int N) {
    int node = (blockIdx.x * blockDim.x + threadIdx.x) >> 6;
    int lane = threadIdx.x & 63;
    if (node >= N) return;
    const int beg = row_ptr[node], end = row_ptr[node + 1];
    const float rdeg = 1.0f / fmaxf((float)(end - beg), 1.0f);
    const int off = lane * 2;

    float a0x = 0, a0y = 0, a1x = 0, a1y = 0, a2x = 0, a2y = 0, a3x = 0, a3y = 0;
    int i = beg;
    for (; i + 4 <= end; i += 4) {
        int s0 = col_src[i], s1 = col_src[i + 1], s2 = col_src[i + 2], s3 = col_src[i + 3];
        unsigned int u0 = *(const unsigned int*)&t[(size_t)s0 * 128 + off];
        unsigned int u1 = *(const unsigned int*)&t[(size_t)s1 * 128 + off];
        unsigned int u2 = *(const unsigned int*)&t[(size_t)s2 * 128 + off];
        unsigned int u3 = *(const unsigned int*)&t[(size_t)s3 * 128 + off];
        a0x += bflo(u0); a0y += bfhi(u0);
        a1x += bflo(u1); a1y += bfhi(u1);
        a2x += bflo(u2); a2y += bfhi(u2);
        a3x += bflo(u3); a3y += bfhi(u3);
    }
    for (; i < end; ++i) {
        unsigned int u = *(const unsigned int*)&t[(size_t)col_src[i] * 128 + off];
        a0x += bflo(u); a0y += bfhi(u);
    }
    float ax = (a0x + a1x) + (a2x + a3x);
    float ay = (a0y + a1y) + (a2y + a3y);
    unsigned int ub = *(const unsigned int*)&base[(size_t)node * 128 + off];
    float ox = fmaxf(bflo(ub) + ax * rdeg, 0.0f);
    float oy = fmaxf(bfhi(ub) + ay * rdeg, 0.0f);
    *(unsigned int*)&out[(size_t)node * 128 + off] = pack2(ox, oy);
}

// ===========================================================================
// Layer-2 MFMA dual GEMM, bf16 input (h1), weights from Wt2; bf16 outputs.
// ===========================================================================
__global__ __launch_bounds__(256) void gemm2_kernel(
        const unsigned short* __restrict__ x,   // h1 bf16 [N][128]
        const unsigned short* __restrict__ Wt,  // [128][128] bf16
        const float* __restrict__ bias,
        unsigned short* __restrict__ hsb2,
        unsigned short* __restrict__ t2,
        int N) {
    constexpr int DOUT = OUT_DIM;
    constexpr int K   = 128;
    constexpr int MT  = 64;
    constexpr int SL  = 2 * DOUT / 4;   // 32
    constexpr int TN  = SL / 16;        // 2
    constexpr int TM  = MT / 16;        // 4
    constexpr int KS  = K / 32;         // 4
    constexpr int LDA = K + 8;

    __shared__ unsigned short sA[MT][LDA];

    const int tid = threadIdx.x;
    const int w   = tid >> 6;
    const int l   = tid & 63;
    const int l16 = l & 15;
    const int lhi = l >> 4;
    const int n0  = (int)blockIdx.x * MT;

    // ---- stage A tile: 64 x 128 bf16 copy ----
    #pragma unroll
    for (int it = 0; it < 4; ++it) {
        int flat = it * 256 + tid;
        int r  = flat >> 4;
        int c8 = flat & 15;
        uint4 v = {0, 0, 0, 0};
        if (n0 + r < N) v = *(const uint4*)&x[(size_t)(n0 + r) * K + c8 * 8];
        *(uint4*)&sA[r][c8 * 8] = v;
    }

    bf16x8 breg[TN][KS];
    float  bval[TN];
    #pragma unroll
    for (int tn = 0; tn < TN; ++tn) {
        const int c = w * SL + tn * 16 + l16;
        bval[tn] = (c < DOUT) ? bias[c] : 0.0f;
        #pragma unroll
        for (int ks = 0; ks < KS; ++ks)
            breg[tn][ks] = *(const bf16x8*)&Wt[c * 128 + ks * 32 + lhi * 8];
    }
    __syncthreads();

    f32x4 acc[TN][TM];
    #pragma unroll
    for (int tn = 0; tn < TN; ++tn)
        #pragma unroll
        for (int tm = 0; tm < TM; ++tm)
            acc[tn][tm] = (f32x4){0.0f, 0.0f, 0.0f, 0.0f};

    #pragma unroll
    for (int ks = 0; ks < KS; ++ks) {
        bf16x8 a[TM];
        #pragma unroll
        for (int tm = 0; tm < TM; ++tm)
            a[tm] = *(const bf16x8*)&sA[tm * 16 + l16][ks * 32 + lhi * 8];
        #pragma unroll
        for (int tn = 0; tn < TN; ++tn)
            #pragma unroll
            for (int tm = 0; tm < TM; ++tm)
                acc[tn][tm] = __builtin_amdgcn_mfma_f32_16x16x32_bf16(
                    a[tm], breg[tn][ks], acc[tn][tm], 0, 0, 0);
    }

    #pragma unroll
    for (int tn = 0; tn < TN; ++tn) {
        const int c = w * SL + tn * 16 + l16;
        const bool self = (c < DOUT);
        const int cc = self ? c : c - DOUT;
        #pragma unroll
        for (int tm = 0; tm < TM; ++tm) {
            #pragma unroll
            for (int r = 0; r < 4; ++r) {
                const int n = n0 + tm * 16 + lhi * 4 + r;
                if (n < N) {
                    const unsigned short v = f2bf(acc[tn][tm][r] + bval[tn]);
                    if (self) hsb2[(size_t)n * DOUT + cc] = v;
                    else      t2  [(size_t)n * DOUT + cc] = v;
                }
            }
        }
    }
}

// ===========================================================================
// Gather-mean layer 2 (D=64): 32 lanes per node (2 nodes/wave), bf16 base/out.
// ===========================================================================
__global__ void gather_mean64_kernel(const unsigned short* __restrict__ t,
                                     const unsigned short* __restrict__ base,
                                     const int* __restrict__ row_ptr,
                                     const unsigned short* __restrict__ col_src,
                                     unsigned short* __restrict__ out, int N) {
    int tid  = blockIdx.x * blockDim.x + threadIdx.x;
    int node = (tid >> 6) * 2 + ((tid >> 5) & 1);
    int m    = tid & 31;
    if (node >= N) return;
    const int beg = row_ptr[node], end = row_ptr[node + 1];
    const float rdeg = 1.0f / fmaxf((float)(end - beg), 1.0f);
    const int off = m * 2;

    float a0x = 0, a0y = 0, a1x = 0, a1y = 0, a2x = 0, a2y = 0, a3x = 0, a3y = 0;
    int i = beg;
    for (; i + 4 <= end; i += 4) {
        int s0 = col_src[i], s1 = col_src[i + 1], s2 = col_src[i + 2], s3 = col_src[i + 3];
        unsigned int u0 = *(const unsigned int*)&t[(size_t)s0 * 64 + off];
        unsigned int u1 = *(const unsigned int*)&t[(size_t)s1 * 64 + off];
        unsigned int u2 = *(const unsigned int*)&t[(size_t)s2 * 64 + off];
        unsigned int u3 = *(const unsigned int*)&t[(size_t)s3 * 64 + off];
        a0x += bflo(u0); a0y += bfhi(u0);
        a1x += bflo(u1); a1y += bfhi(u1);
        a2x += bflo(u2); a2y += bfhi(u2);
        a3x += bflo(u3); a3y += bfhi(u3);
    }
    for (; i < end; ++i) {
        unsigned int u = *(const unsigned int*)&t[(size_t)col_src[i] * 64 + off];
        a0x += bflo(u); a0y += bfhi(u);
    }
    float ax = (a0x + a1x) + (a2x + a3x);
    float ay = (a0y + a1y) + (a2y + a3y);
    unsigned int ub = *(const unsigned int*)&base[(size_t)node * 64 + off];
    *(unsigned int*)&out[(size_t)node * 64 + off] =
        pack2(bflo(ub) + ax * rdeg, bfhi(ub) + ay * rdeg);
}

// ===========================================================================
// Edge dot on bf16 h (D=64, 128B rows): 4 lanes/edge, 2x uint4 per row per
// lane (4 independent 16B gathers -> MLP), 2-step shfl reduce.
// ===========================================================================
__global__ void edge_dot_kernel(const unsigned short* __restrict__ h,
                                const int* __restrict__ src,
                                const int* __restrict__ dst,
                                const int* __restrict__ nsrc,
                                const int* __restrict__ ndst,
                                float* __restrict__ out,
                                int E) {
    int tid = blockIdx.x * blockDim.x + threadIdx.x;
    int eg = tid >> 2;
    int l  = tid & 3;
    if (eg >= 2 * E) return;
    int s, t;
    if (eg < E) { s = src[eg];      t = dst[eg]; }
    else        { s = nsrc[eg - E]; t = ndst[eg - E]; }
    const uint4* pa = (const uint4*)&h[(size_t)s * OUT_DIM + l * 16];
    const uint4* pb = (const uint4*)&h[(size_t)t * OUT_DIM + l * 16];
    uint4 a0 = pa[0], a1 = pa[1];
    uint4 b0 = pb[0], b1 = pb[1];
    float v = dot8(a0, b0) + dot8(a1, b1);
    v += __shfl_xor(v, 2, 4);
    v += __shfl_xor(v, 1, 4);
    if (l == 0) out[eg] = v;
}

extern "C" void kernel_launch(void* const* d_in, const int* in_sizes, int n_in,
                              void* d_out, int out_size, void* d_ws, size_t ws_size,
                              hipStream_t stream) {
    const float* feat = (const float*)d_in[0];
    const float* Ws1  = (const float*)d_in[1];
    const float* Wn1  = (const float*)d_in[2];
    const float* b1   = (const float*)d_in[3];
    const float* Ws2  = (const float*)d_in[4];
    const float* Wn2  = (const float*)d_in[5];
    const float* b2   = (const float*)d_in[6];
    const int* src  = (const int*)d_in[7];
    const int* dst  = (const int*)d_in[8];
    const int* nsrc = (const int*)d_in[9];
    const int* ndst = (const int*)d_in[10];
    const int E = in_sizes[7];
    const int N = in_sizes[0] / IN_DIM;
    const int NB = (N + 255) / 256;
    const int NT = (N + 63) / 64;           // MFMA node tiles
    const int FB = (E + 1023) / 1024;       // scatter blocks
    const int HB = (E + 255) / 256;         // hist blocks

    // ---- workspace layout (16B-aligned big arrays first) ----
    char* wsb = (char*)d_ws;
    unsigned short* Wt1  = (unsigned short*)wsb;                         // [256][128]
    unsigned short* Wt2  = Wt1 + 256 * 128;                              // [128][128]
    unsigned short* t1   = Wt2 + 128 * 128;                              // N*128 bf16
    unsigned short* hs1b = t1 + (size_t)N * HID_DIM;                     // N*128 bf16
    unsigned short* h1   = hs1b + (size_t)N * HID_DIM;                   // N*128 bf16
    unsigned short* t2   = h1 + (size_t)N * HID_DIM;                     // N*64 bf16
    unsigned short* hs2b = t2 + (size_t)N * OUT_DIM;                     // N*64 bf16
    unsigned short* h2   = hs2b + (size_t)N * OUT_DIM;                   // N*64 bf16
    int* cnt             = (int*)(h2 + (size_t)N * OUT_DIM);             // N
    int* row_ptr         = cnt + N;                                      // N+1
    int* partial         = row_ptr + N + 1;                              // 256
    unsigned short* rank    = (unsigned short*)(partial + 256);          // E
    unsigned short* col_src = rank + E;                                  // E

    // ---- zero cnt ----
    {
        int n4 = (N + 3) / 4;
        zero_cnt_kernel<<<(n4 + 255) / 256, 256, 0, stream>>>((uint4*)cnt, n4);
    }

    // ---- CSR build + weight transpose (fused) ----
    wtrans_hist_kernel<<<24 + HB, 256, 0, stream>>>(
        Ws1, Wn1, Ws2, Wn2, Wt1, Wt2, dst, cnt, rank, E);
    block_sums_kernel<<<NB, 256, 0, stream>>>(cnt, partial, N);
    scan_chunks_kernel<<<NB, 256, 0, stream>>>(cnt, partial, row_ptr, N, NB);

    // ---- Layer 1 GEMM (MT=64, 1 tile/block) fused with non-atomic scatter ----
    gemm1_fill_kernel<<<FB + NT, 256, 0, stream>>>(
        feat, Wt1, b1, hs1b, t1, N, FB,
        src, dst, row_ptr, rank, col_src, E);

    // ---- Layer 1 gather-mean + relu -> h1 (bf16; one wave per node) ----
    gather_mean128_kernel<<<(N * 64 + 255) / 256, 256, 0, stream>>>(
        t1, hs1b, row_ptr, col_src, h1, N);

    // ---- Layer 2 GEMM (bf16 input) ----
    gemm2_kernel<<<NT, 256, 0, stream>>>(
        h1, Wt2, b2, hs2b, t2, N);

    // ---- Layer 2 gather-mean -> h2 (bf16) ----
    {
        int waves = (N + 1) / 2;
        gather_mean64_kernel<<<(waves * 64 + 255) / 256, 256, 0, stream>>>(
            t2, hs2b, row_ptr, col_src, h2, N);
    }

    // ---- Edge dots (4 lanes/edge) ----
    {
        int total = 2 * E * 4;
        edge_dot_kernel<<<(total + 255) / 256, 256, 0, stream>>>(
            h2, src, dst, nsrc, ndst, (float*)d_out, E);
    }
}